// Round 5
// baseline (956.437 us; speedup 1.0000x reference)
//
#include <hip/hip_runtime.h>
#include <hip/hip_bf16.h>
#include <stdint.h>

typedef _Float16 half8 __attribute__((ext_vector_type(8)));
typedef float f32x4 __attribute__((ext_vector_type(4)));

#define DDIM 256
#define KCODES 4096
#define BM 128
#define BN 256
#define NCH 8                  // 32-dim chunks per row
#define TILES (KCODES / BN)    // 16
#define STEPS (TILES * NCH)    // 128
#define DELTA 0.02f
#define FLT_BIG 3.4e38f

#define GLOAD_LDS(gsrc, ldst)                                                        \
    __builtin_amdgcn_global_load_lds(                                                \
        (const __attribute__((address_space(1))) void*)(const void*)(gsrc),          \
        (__attribute__((address_space(3))) void*)(void*)(ldst), 16, 0, 0)

// ---------- fp32 -> hi/lo fp16, layout [row][ch(8)][slot(8)] half8 ----------
// slots per 32-dim chunk: 0-3 = hi quads (dims q*8..q*8+7), 4-7 = lo quads
__global__ void cvt_hl_kernel(const float* __restrict__ src, half8* __restrict__ dst) {
    int gid = blockIdx.x * 256 + threadIdx.x;
    int p = gid & 7;
    int ch = (gid >> 3) & 7;
    long row = gid >> 6;
    int part = p >> 2, quad = p & 3;
    const float* s = src + row * DDIM + ch * 32 + quad * 8;
    half8 h;
    #pragma unroll
    for (int j = 0; j < 8; ++j) {
        float v = s[j];
        _Float16 hi = (_Float16)v;
        h[j] = part ? (_Float16)(v - (float)hi) : hi;
    }
    dst[gid] = h;
}

__global__ void enorm_kernel(const float* __restrict__ cb, float* __restrict__ en, int K) {
    int gid = blockIdx.x * blockDim.x + threadIdx.x;
    int code = gid >> 6;
    int lane = threadIdx.x & 63;
    if (code >= K) return;
    const float4 v = *reinterpret_cast<const float4*>(&cb[(size_t)code * DDIM + lane * 4]);
    float s = v.x * v.x + v.y * v.y + v.z * v.z + v.w * v.w;
    #pragma unroll
    for (int off = 32; off > 0; off >>= 1) s += __shfl_xor(s, off, 64);
    if (lane == 0) en[code] = s;
}

// per-wave staging: 6 x global_load_lds (A regions 0-15, B regions 16-47)
__device__ __forceinline__ void stage_step(int st, int w, int lane, int brow,
                                           const half8* __restrict__ x16,
                                           const half8* __restrict__ cb16,
                                           half8* Ab, half8* Bb) {
    const int ct = st >> 3, ch = st & 7;
    #pragma unroll
    for (int i = 0; i < 6; ++i) {
        const int r = w * 6 + i;
        if (r < 16) {
            int sl = r * 64 + lane;
            int row = sl >> 3, p = sl & 7;
            const half8* src = x16 + ((size_t)(brow + row) * NCH + ch) * 8 + (p ^ (row & 7));
            GLOAD_LDS(src, Ab + r * 64);
        } else {
            int sl = (r - 16) * 64 + lane;
            int row = sl >> 3, p = sl & 7;
            const half8* src = cb16 + ((size_t)(ct * BN + row) * NCH + ch) * 8 + (p ^ (row & 7));
            GLOAD_LDS(src, Bb + (r - 16) * 64);
        }
    }
}

// ---------------- main: pipelined MFMA GEMM + fused argmin + gap flag ----------------
__global__ __launch_bounds__(512, 2)
void vq_mfma_kernel(const half8* __restrict__ x16, const half8* __restrict__ cb16,
                    const float* __restrict__ en, int* __restrict__ bidx_out,
                    int* __restrict__ list, int* __restrict__ counter) {
    __shared__ __align__(16) half8 Abuf[2][BM * 8];   // 2 x 16 KB
    __shared__ __align__(16) half8 Bbuf[2][BN * 8];   // 2 x 32 KB
    __shared__ float en_lds[KCODES];                  // 16 KB
    __shared__ float red_d[4][BM];
    __shared__ float red_d2[4][BM];
    __shared__ int   red_i[4][BM];

    const int tid = threadIdx.x;
    const int lane = tid & 63;
    const int w = tid >> 6;
    const int wr = w >> 2, wc = w & 3;       // 2 x 4 waves, wave-tile 64x64
    const int l15 = lane & 15, l4 = lane >> 4;
    const int brow = blockIdx.x * BM;

    for (int i = tid; i < KCODES; i += 512) en_lds[i] = en[i];

    // prologue: stage steps 0,1
    stage_step(0, w, lane, brow, x16, cb16, Abuf[0], Bbuf[0]);
    stage_step(1, w, lane, brow, x16, cb16, Abuf[1], Bbuf[1]);
    __syncthreads();   // drains prologue vmcnt + en_lds writes

    float best[16], best2[16];
    int bid[16];
    #pragma unroll
    for (int i = 0; i < 16; ++i) { best[i] = FLT_BIG; best2[i] = FLT_BIG; bid[i] = 0; }

    f32x4 acc[4][4];

    #pragma unroll 2
    for (int s = 0; s < STEPS; ++s) {
        const int b = s & 1;
        if ((s & 7) == 0) {
            #pragma unroll
            for (int m = 0; m < 4; ++m)
                #pragma unroll
                for (int n = 0; n < 4; ++n) acc[m][n] = (f32x4){0.f, 0.f, 0.f, 0.f};
        }
        const half8* Ap = Abuf[b];
        const half8* Bp = Bbuf[b];
        half8 ah[4], al[4], bh[4], bl[4];
        #pragma unroll
        for (int m = 0; m < 4; ++m) {
            int row = wr * 64 + m * 16 + l15;
            int base = row * 8, sw = row & 7;
            ah[m] = Ap[base + (l4 ^ sw)];
            al[m] = Ap[base + ((4 + l4) ^ sw)];
        }
        #pragma unroll
        for (int n = 0; n < 4; ++n) {
            int col = wc * 64 + n * 16 + l15;
            int base = col * 8, sw = col & 7;
            bh[n] = Bp[base + (l4 ^ sw)];
            bl[n] = Bp[base + ((4 + l4) ^ sw)];
        }
        asm volatile("s_waitcnt lgkmcnt(0)" ::: "memory");
        __builtin_amdgcn_sched_barrier(0);
        __builtin_amdgcn_s_barrier();          // all waves done reading buf b

        const bool more = (s + 2 < STEPS);
        if (more) stage_step(s + 2, w, lane, brow, x16, cb16, Abuf[b], Bbuf[b]);

        __builtin_amdgcn_s_setprio(1);
        #pragma unroll
        for (int m = 0; m < 4; ++m)
            #pragma unroll
            for (int n = 0; n < 4; ++n) {
                acc[m][n] = __builtin_amdgcn_mfma_f32_16x16x32_f16(ah[m], bh[n], acc[m][n], 0, 0, 0);
                acc[m][n] = __builtin_amdgcn_mfma_f32_16x16x32_f16(al[m], bh[n], acc[m][n], 0, 0, 0);
                acc[m][n] = __builtin_amdgcn_mfma_f32_16x16x32_f16(ah[m], bl[n], acc[m][n], 0, 0, 0);
            }
        __builtin_amdgcn_s_setprio(0);

        if ((s & 7) == 7) {   // tile epilogue: dist = ||e||^2 - 2*dot
            const int c0 = (s >> 3) * BN;
            #pragma unroll
            for (int n = 0; n < 4; ++n) {
                int code = c0 + wc * 64 + n * 16 + l15;
                float e = en_lds[code];
                #pragma unroll
                for (int m = 0; m < 4; ++m) {
                    #pragma unroll
                    for (int r = 0; r < 4; ++r) {
                        float dist = fmaf(-2.f, acc[m][n][r], e);
                        int ri = m * 4 + r;
                        if (dist < best[ri]) {
                            best2[ri] = best[ri]; best[ri] = dist; bid[ri] = code;
                        } else if (dist < best2[ri]) {
                            best2[ri] = dist;
                        }
                    }
                }
            }
        }

        if (more) { asm volatile("s_waitcnt vmcnt(6)" ::: "memory"); }
        else      { asm volatile("s_waitcnt vmcnt(0)" ::: "memory"); }
        __builtin_amdgcn_s_barrier();          // buf b^1 ready for step s+1
    }

    // ---- cross-lane merge (16 lanes share the same rows) ----
    #pragma unroll
    for (int ri = 0; ri < 16; ++ri) {
        float d = best[ri], d2 = best2[ri];
        int ix = bid[ri];
        #pragma unroll
        for (int off = 1; off < 16; off <<= 1) {
            float od = __shfl_xor(d, off, 64);
            float od2 = __shfl_xor(d2, off, 64);
            int oi = __shfl_xor(ix, off, 64);
            if (od < d || (od == d && oi < ix)) {
                d2 = fminf(d, od2); d = od; ix = oi;
            } else {
                d2 = fminf(d2, od);
            }
        }
        if (l15 == 0) {
            int row = wr * 64 + (ri >> 2) * 16 + l4 * 4 + (ri & 3);
            red_d[wc][row] = d;
            red_d2[wc][row] = d2;
            red_i[wc][row] = ix;
        }
    }
    __syncthreads();

    // ---- cross-wave merge + write + flag append ----
    if (tid < BM) {
        float d = red_d[0][tid], d2 = red_d2[0][tid];
        int ix = red_i[0][tid];
        #pragma unroll
        for (int q = 1; q < 4; ++q) {
            float od = red_d[q][tid], od2 = red_d2[q][tid];
            int oi = red_i[q][tid];
            if (od < d || (od == d && oi < ix)) {
                d2 = fminf(d, od2); d = od; ix = oi;
            } else {
                d2 = fminf(d2, od);
            }
        }
        bidx_out[brow + tid] = ix;
        if (d2 - d < DELTA) {
            int pos = atomicAdd(counter, 1);
            list[pos] = brow + tid;
        }
    }
}

// ---------------- exact fp32 rescan: compacted list, wave-per-code coalesced ----------------
__global__ __launch_bounds__(256)
void rescan_kernel(const float* __restrict__ x, const float* __restrict__ cb,
                   const float* __restrict__ en, const int* __restrict__ list,
                   const int* __restrict__ counter, int* __restrict__ bidx) {
    __shared__ __align__(16) float4 xrow4[64];
    __shared__ float wd[4];
    __shared__ int wi[4];
    const int tid = threadIdx.x;
    const int w = tid >> 6;
    const int lane = tid & 63;
    const int cnt = *counter;

    for (int it = blockIdx.x; it < cnt; it += gridDim.x) {
        const int row = list[it];
        __syncthreads();
        if (tid < 64) xrow4[tid] = ((const float4*)&x[(size_t)row * DDIM])[tid];
        __syncthreads();
        const float4 xv = xrow4[lane];
        float bd = FLT_BIG;
        int bi = 0;
        for (int i = 0; i < KCODES / 4; ++i) {
            int code = i * 4 + w;
            const float4 c4 = ((const float4*)&cb[(size_t)code * DDIM])[lane];
            float s = xv.x * c4.x + xv.y * c4.y + xv.z * c4.z + xv.w * c4.w;
            #pragma unroll
            for (int off = 1; off < 64; off <<= 1) s += __shfl_xor(s, off, 64);
            float dist = fmaf(-2.f, s, en[code]);
            if (dist < bd) { bd = dist; bi = code; }
        }
        if (lane == 0) { wd[w] = bd; wi[w] = bi; }
        __syncthreads();
        if (tid == 0) {
            float d = wd[0]; int ix = wi[0];
            #pragma unroll
            for (int q = 1; q < 4; ++q) {
                if (wd[q] < d || (wd[q] == d && wi[q] < ix)) { d = wd[q]; ix = wi[q]; }
            }
            bidx[row] = ix;
        }
    }
}

// ---------------- gather + loss + indices ----------------
__global__ void gather_kernel(const float* __restrict__ x, const float* __restrict__ cb,
                              const int* __restrict__ bidx, float* __restrict__ out,
                              float* __restrict__ loss_accum, int N) {
    __shared__ float wsum[4];
    const int tid = threadIdx.x;
    const int brow = blockIdx.x * BM;
    const size_t ND = (size_t)N * DDIM;
    if (tid < BM) out[ND + 1 + brow + tid] = (float)bidx[brow + tid];
    float lsum = 0.f;
    #pragma unroll 4
    for (int p = 0; p < 32; ++p) {
        int i = tid + p * 256;
        int row = i >> 6;
        int c4 = (i & 63) << 2;
        int code = bidx[brow + row];
        const float4 q = *reinterpret_cast<const float4*>(&cb[(size_t)code * DDIM + c4]);
        const float4 xv = *reinterpret_cast<const float4*>(&x[(size_t)(brow + row) * DDIM + c4]);
        float d0 = xv.x - q.x, d1 = xv.y - q.y, d2 = xv.z - q.z, d3 = xv.w - q.w;
        lsum += d0 * d0 + d1 * d1 + d2 * d2 + d3 * d3;
        *reinterpret_cast<float4*>(&out[(size_t)(brow + row) * DDIM + c4]) = q;
    }
    #pragma unroll
    for (int off = 32; off > 0; off >>= 1) lsum += __shfl_xor(lsum, off, 64);
    if ((tid & 63) == 0) wsum[tid >> 6] = lsum;
    __syncthreads();
    if (tid == 0) {
        float tot = wsum[0] + wsum[1] + wsum[2] + wsum[3];
        atomicAdd(loss_accum, tot * (0.25f / (float)ND));
    }
}

__global__ void loss_fin_kernel(const float* __restrict__ loss_accum,
                                float* __restrict__ out, size_t off) {
    if (blockIdx.x == 0 && threadIdx.x == 0) out[off] = *loss_accum;
}

extern "C" void kernel_launch(void* const* d_in, const int* in_sizes, int n_in,
                              void* d_out, int out_size, void* d_ws, size_t ws_size,
                              hipStream_t stream) {
    const float* x = (const float*)d_in[0];
    const float* cb = (const float*)d_in[1];
    const int N = in_sizes[0] / DDIM;    // 65536
    const int K = in_sizes[1] / DDIM;    // 4096
    float* out = (float*)d_out;

    // x16 (64 MB) lives in out[0 .. N*D) — overwritten by gather afterwards
    half8* x16 = (half8*)d_out;

    // workspace: cb16 (4 MB) + small buffers
    half8* cb16 = (half8*)d_ws;
    char* p = (char*)d_ws + (4 << 20);
    float* en = (float*)p;                  p += (size_t)K * 4;
    int* bidx = (int*)p;                    p += (size_t)N * 4;
    int* list = (int*)p;                    p += (size_t)N * 4;
    int* counter = (int*)p;                 p += 64;
    float* loss_accum = (float*)p;

    hipMemsetAsync(counter, 0, sizeof(int), stream);
    hipMemsetAsync(loss_accum, 0, sizeof(float), stream);
    cvt_hl_kernel<<<(N * 64) / 256, 256, 0, stream>>>(x, x16);
    cvt_hl_kernel<<<(K * 64) / 256, 256, 0, stream>>>(cb, cb16);
    enorm_kernel<<<(K * 64) / 256, 256, 0, stream>>>(cb, en, K);
    vq_mfma_kernel<<<N / BM, 512, 0, stream>>>(x16, cb16, en, bidx, list, counter);
    rescan_kernel<<<512, 256, 0, stream>>>(x, cb, en, list, counter, bidx);
    gather_kernel<<<N / BM, 256, 0, stream>>>(x, cb, bidx, out, loss_accum, N);
    loss_fin_kernel<<<1, 64, 0, stream>>>(loss_accum, out, (size_t)N * DDIM);
}

// Round 6
// 903.235 us; speedup vs baseline: 1.0589x; 1.0589x over previous
//
#include <hip/hip_runtime.h>
#include <stdint.h>

typedef _Float16 half8 __attribute__((ext_vector_type(8)));
typedef float f32x4 __attribute__((ext_vector_type(4)));

#define DDIM 256
#define KCODES 4096
#define BM 128
#define BN 256
#define NCH 8                  // 32-dim chunks per row
#define STEPS 128              // 16 tiles x 8 chunks
#define DELTA 0.02f
#define FLT_BIG 3.4e38f

#define GLOAD_LDS(gsrc, ldst)                                                        \
    __builtin_amdgcn_global_load_lds(                                                \
        (const __attribute__((address_space(1))) void*)(const void*)(gsrc),          \
        (__attribute__((address_space(3))) void*)(void*)(ldst), 16, 0, 0)

// ---------- fp32 -> hi/lo fp16, layout [row][ch(8)][slot(8)] half8 ----------
// slots per 32-dim chunk: 0-3 = hi quads (dims q*8..q*8+7), 4-7 = lo quads
__global__ void cvt_hl_kernel(const float* __restrict__ src, half8* __restrict__ dst) {
    int gid = blockIdx.x * 256 + threadIdx.x;
    int p = gid & 7;
    int ch = (gid >> 3) & 7;
    long row = gid >> 6;
    int part = p >> 2, quad = p & 3;
    const float* s = src + row * DDIM + ch * 32 + quad * 8;
    half8 h;
    #pragma unroll
    for (int j = 0; j < 8; ++j) {
        float v = s[j];
        _Float16 hi = (_Float16)v;
        h[j] = part ? (_Float16)(v - (float)hi) : hi;
    }
    dst[gid] = h;
}

__global__ void enorm_kernel(const float* __restrict__ cb, float* __restrict__ en, int K) {
    int gid = blockIdx.x * blockDim.x + threadIdx.x;
    int code = gid >> 6;
    int lane = threadIdx.x & 63;
    if (code >= K) return;
    const float4 v = *reinterpret_cast<const float4*>(&cb[(size_t)code * DDIM + lane * 4]);
    float s = v.x * v.x + v.y * v.y + v.z * v.z + v.w * v.w;
    #pragma unroll
    for (int off = 32; off > 0; off >>= 1) s += __shfl_xor(s, off, 64);
    if (lane == 0) en[code] = s;
}

// ---------------- main: pipelined MFMA GEMM + argmin + fused gather/loss ----------------
__global__ __launch_bounds__(512, 2)
void vq_mfma_kernel(const half8* x16, const half8* __restrict__ cb16,
                    const float* __restrict__ en, const float* __restrict__ x,
                    const float* __restrict__ cb, float* out,
                    int* __restrict__ list, int* __restrict__ counter,
                    float* __restrict__ loss_accum, int N) {
    __shared__ __align__(16) half8 Abuf[2][BM * 8];   // 2 x 16 KB
    __shared__ __align__(16) half8 Bbuf[2][BN * 8];   // 2 x 32 KB
    __shared__ float en_lds[KCODES];                  // 16 KB
    __shared__ float red_d[4][BM];
    __shared__ float red_d2[4][BM];
    __shared__ int   red_i[4][BM];
    __shared__ int   binfo[BM];
    __shared__ float wsum[8];

    const int tid = threadIdx.x;
    const int lane = tid & 63;
    const int w = tid >> 6;
    const int wr = w >> 2, wc = w & 3;       // 2 x 4 waves, wave-tile 64x64
    const int l15 = lane & 15, l4 = lane >> 4;
    const int brow = blockIdx.x * BM;
    const size_t ND = (size_t)N * DDIM;

    for (int i = tid; i < KCODES; i += 512) en_lds[i] = en[i];

    // ---- persistent stage pointers; regions: A r=w+8i (i<2), B q=w+8j (j<4) ----
    const int lrow = lane >> 3;          // row within 8-row region
    const int swz = (lane & 7) ^ lrow;   // pre-swizzled source slot
    const half8* pA0 = x16 + ((size_t)(brow + w * 8      + lrow) * NCH) * 8 + swz;
    const half8* pA1 = x16 + ((size_t)(brow + (w + 8) * 8 + lrow) * NCH) * 8 + swz;
    const half8* pB0 = cb16 + ((size_t)((w     ) * 8 + lrow) * NCH) * 8 + swz;
    const half8* pB1 = cb16 + ((size_t)((w +  8) * 8 + lrow) * NCH) * 8 + swz;
    const half8* pB2 = cb16 + ((size_t)((w + 16) * 8 + lrow) * NCH) * 8 + swz;
    const half8* pB3 = cb16 + ((size_t)((w + 24) * 8 + lrow) * NCH) * 8 + swz;

#define STAGE(b_) do {                                      \
        GLOAD_LDS(pA0, &Abuf[b_][(w     ) * 64]);           \
        GLOAD_LDS(pA1, &Abuf[b_][(w +  8) * 64]);           \
        GLOAD_LDS(pB0, &Bbuf[b_][(w     ) * 64]);           \
        GLOAD_LDS(pB1, &Bbuf[b_][(w +  8) * 64]);           \
        GLOAD_LDS(pB2, &Bbuf[b_][(w + 16) * 64]);           \
        GLOAD_LDS(pB3, &Bbuf[b_][(w + 24) * 64]);           \
    } while (0)

#define ADVANCE(t_) do {                                    \
        int dA = (((t_) & 7) == 7) ? -56 : 8;               \
        int dB = (((t_) & 7) == 7) ? 16328 : 8;             \
        pA0 += dA; pA1 += dA;                               \
        pB0 += dB; pB1 += dB; pB2 += dB; pB3 += dB;         \
    } while (0)

    // ---- LDS frag read bases (halfword units); m/n via constant offsets ----
    const int sw7 = l15 & 7;
    const _Float16* A0 = (const _Float16*)Abuf;
    const _Float16* B0 = (const _Float16*)Bbuf;
    const _Float16* aH = A0 + wr * 4096 + l15 * 64 + ((l4    ) ^ sw7) * 8;
    const _Float16* aL = A0 + wr * 4096 + l15 * 64 + ((l4 + 4) ^ sw7) * 8;
    const _Float16* bH = B0 + wc * 4096 + l15 * 64 + ((l4    ) ^ sw7) * 8;
    const _Float16* bL = B0 + wc * 4096 + l15 * 64 + ((l4 + 4) ^ sw7) * 8;

    // prologue: stage steps 0,1
    STAGE(0); ADVANCE(0);
    STAGE(1); ADVANCE(1);
    __syncthreads();   // drains prologue vmcnt + en_lds writes

    float best[16], best2[16];
    int bid[16];
    #pragma unroll
    for (int i = 0; i < 16; ++i) { best[i] = FLT_BIG; best2[i] = FLT_BIG; bid[i] = 0; }

    f32x4 acc[4][4];

    #pragma unroll 2
    for (int s = 0; s < STEPS; ++s) {
        const int b = s & 1;
        if ((s & 7) == 0) {
            #pragma unroll
            for (int m = 0; m < 4; ++m)
                #pragma unroll
                for (int n = 0; n < 4; ++n) acc[m][n] = (f32x4){0.f, 0.f, 0.f, 0.f};
        }
        const int ao = b ? 8192 : 0;
        const int bo = b ? 16384 : 0;
        half8 ah[4], al[4], bh[4], bl[4];
        #pragma unroll
        for (int m = 0; m < 4; ++m) {
            ah[m] = *(const half8*)(aH + ao + m * 1024);
            al[m] = *(const half8*)(aL + ao + m * 1024);
        }
        #pragma unroll
        for (int n = 0; n < 4; ++n) {
            bh[n] = *(const half8*)(bH + bo + n * 1024);
            bl[n] = *(const half8*)(bL + bo + n * 1024);
        }
        asm volatile("s_waitcnt lgkmcnt(0)" ::: "memory");
        __builtin_amdgcn_sched_barrier(0);
        __builtin_amdgcn_s_barrier();          // all waves done reading buf b

        const bool more = (s + 2 < STEPS);
        if (more) { STAGE(b); ADVANCE(s + 2); }

        __builtin_amdgcn_s_setprio(1);
        #pragma unroll
        for (int m = 0; m < 4; ++m)
            #pragma unroll
            for (int n = 0; n < 4; ++n) {
                acc[m][n] = __builtin_amdgcn_mfma_f32_16x16x32_f16(ah[m], bh[n], acc[m][n], 0, 0, 0);
                acc[m][n] = __builtin_amdgcn_mfma_f32_16x16x32_f16(al[m], bh[n], acc[m][n], 0, 0, 0);
                acc[m][n] = __builtin_amdgcn_mfma_f32_16x16x32_f16(ah[m], bl[n], acc[m][n], 0, 0, 0);
            }
        __builtin_amdgcn_s_setprio(0);

        if ((s & 7) == 7) {   // tile epilogue: dist = ||e||^2 - 2*dot
            const int c0 = (s >> 3) * BN;
            #pragma unroll
            for (int n = 0; n < 4; ++n) {
                int code = c0 + wc * 64 + n * 16 + l15;
                float e = en_lds[code];
                #pragma unroll
                for (int m = 0; m < 4; ++m) {
                    #pragma unroll
                    for (int r = 0; r < 4; ++r) {
                        float dist = fmaf(-2.f, acc[m][n][r], e);
                        int ri = m * 4 + r;
                        if (dist < best[ri]) {
                            best2[ri] = best[ri]; best[ri] = dist; bid[ri] = code;
                        } else if (dist < best2[ri]) {
                            best2[ri] = dist;
                        }
                    }
                }
            }
        }

        if (more) { asm volatile("s_waitcnt vmcnt(6)" ::: "memory"); }
        else      { asm volatile("s_waitcnt vmcnt(0)" ::: "memory"); }
        __builtin_amdgcn_s_barrier();          // buf b^1 ready for step s+1
    }
#undef STAGE
#undef ADVANCE

    // ---- cross-lane merge (16 lanes share the same rows) ----
    #pragma unroll
    for (int ri = 0; ri < 16; ++ri) {
        float d = best[ri], d2 = best2[ri];
        int ix = bid[ri];
        #pragma unroll
        for (int off = 1; off < 16; off <<= 1) {
            float od = __shfl_xor(d, off, 64);
            float od2 = __shfl_xor(d2, off, 64);
            int oi = __shfl_xor(ix, off, 64);
            if (od < d || (od == d && oi < ix)) {
                d2 = fminf(d, od2); d = od; ix = oi;
            } else {
                d2 = fminf(d2, od);
            }
        }
        if (l15 == 0) {
            int row = wr * 64 + (ri >> 2) * 16 + l4 * 4 + (ri & 3);
            red_d[wc][row] = d;
            red_d2[wc][row] = d2;
            red_i[wc][row] = ix;
        }
    }
    __syncthreads();

    // ---- cross-wave merge + index write + flag append ----
    if (tid < BM) {
        float d = red_d[0][tid], d2 = red_d2[0][tid];
        int ix = red_i[0][tid];
        #pragma unroll
        for (int q = 1; q < 4; ++q) {
            float od = red_d[q][tid], od2 = red_d2[q][tid];
            int oi = red_i[q][tid];
            if (od < d || (od == d && oi < ix)) {
                d2 = fminf(d, od2); d = od; ix = oi;
            } else {
                d2 = fminf(d2, od);
            }
        }
        int fl = (d2 - d < DELTA) ? 1 : 0;
        out[ND + 1 + brow + tid] = (float)ix;
        binfo[tid] = ix | (fl << 16);
        if (fl) {
            int pos = atomicAdd(counter, 1);
            list[pos] = brow + tid;
        }
    }
    __syncthreads();

    // ---- fused gather + loss (flagged rows: provisional write, no loss) ----
    float lsum = 0.f;
    #pragma unroll 4
    for (int pp = 0; pp < 16; ++pp) {
        int i = tid + pp * 512;       // 0..8191 float4-units
        int row = i >> 6;
        int c4 = (i & 63) << 2;
        int info = binfo[row];
        int code = info & 0xffff;
        const float4 q = *reinterpret_cast<const float4*>(&cb[(size_t)code * DDIM + c4]);
        const float4 xv = *reinterpret_cast<const float4*>(&x[(size_t)(brow + row) * DDIM + c4]);
        float d0 = xv.x - q.x, d1 = xv.y - q.y, d2 = xv.z - q.z, d3 = xv.w - q.w;
        if (!(info >> 16)) lsum += d0 * d0 + d1 * d1 + d2 * d2 + d3 * d3;
        *reinterpret_cast<float4*>(&out[(size_t)(brow + row) * DDIM + c4]) = q;
    }
    #pragma unroll
    for (int off = 32; off > 0; off >>= 1) lsum += __shfl_xor(lsum, off, 64);
    if (lane == 0) wsum[w] = lsum;
    __syncthreads();
    if (tid == 0) {
        float tot = 0.f;
        #pragma unroll
        for (int q = 0; q < 8; ++q) tot += wsum[q];
        atomicAdd(loss_accum, tot * (0.25f / (float)ND));
    }
}

// ---------------- exact fp32 rescan: repairs flagged rows completely ----------------
__global__ __launch_bounds__(256)
void rescan_kernel(const float* __restrict__ x, const float* __restrict__ cb,
                   const float* __restrict__ en, const int* __restrict__ list,
                   const int* __restrict__ counter, float* out,
                   float* __restrict__ loss_accum, int N) {
    __shared__ __align__(16) float4 xrow4[64];
    __shared__ float wd[4];
    __shared__ int wi[4];
    __shared__ float wls[4];
    __shared__ int six;
    const int tid = threadIdx.x;
    const int w = tid >> 6;
    const int lane = tid & 63;
    const int cnt = *counter;
    const size_t ND = (size_t)N * DDIM;

    for (int it = blockIdx.x; it < cnt; it += gridDim.x) {
        const int row = list[it];
        __syncthreads();
        if (tid < 64) xrow4[tid] = ((const float4*)&x[(size_t)row * DDIM])[tid];
        __syncthreads();
        const float4 xv = xrow4[lane];
        float bd = FLT_BIG;
        int bi = 0;
        for (int i = 0; i < KCODES / 4; ++i) {
            int code = i * 4 + w;
            const float4 c4 = ((const float4*)&cb[(size_t)code * DDIM])[lane];
            float s = xv.x * c4.x + xv.y * c4.y + xv.z * c4.z + xv.w * c4.w;
            #pragma unroll
            for (int off = 1; off < 64; off <<= 1) s += __shfl_xor(s, off, 64);
            float dist = fmaf(-2.f, s, en[code]);
            if (dist < bd) { bd = dist; bi = code; }   // ascending code order per wave
        }
        if (lane == 0) { wd[w] = bd; wi[w] = bi; }
        __syncthreads();
        if (tid == 0) {
            float d = wd[0]; int ix = wi[0];
            #pragma unroll
            for (int q = 1; q < 4; ++q) {
                if (wd[q] < d || (wd[q] == d && wi[q] < ix)) { d = wd[q]; ix = wi[q]; }
            }
            six = ix;
            out[ND + 1 + row] = (float)ix;
        }
        __syncthreads();
        const int ix = six;
        // quantized write + exact loss contribution for this row
        float c = cb[(size_t)ix * DDIM + tid];
        float xs = ((const float*)xrow4)[tid];
        out[(size_t)row * DDIM + tid] = c;
        float dd = xs - c;
        float ss = dd * dd;
        #pragma unroll
        for (int off = 32; off > 0; off >>= 1) ss += __shfl_xor(ss, off, 64);
        if (lane == 0) wls[w] = ss;
        __syncthreads();
        if (tid == 0) {
            float tot = wls[0] + wls[1] + wls[2] + wls[3];
            atomicAdd(loss_accum, tot * (0.25f / (float)ND));
        }
    }
}

__global__ void loss_fin_kernel(const float* __restrict__ loss_accum,
                                float* __restrict__ out, size_t off) {
    if (blockIdx.x == 0 && threadIdx.x == 0) out[off] = *loss_accum;
}

extern "C" void kernel_launch(void* const* d_in, const int* in_sizes, int n_in,
                              void* d_out, int out_size, void* d_ws, size_t ws_size,
                              hipStream_t stream) {
    const float* x = (const float*)d_in[0];
    const float* cb = (const float*)d_in[1];
    const int N = in_sizes[0] / DDIM;    // 65536
    const int K = in_sizes[1] / DDIM;    // 4096
    float* out = (float*)d_out;

    // x16 (64 MB) lives in out[0 .. N*D) — each block reads only its own rows,
    // then overwrites them in its fused gather epilogue
    half8* x16 = (half8*)d_out;

    // workspace: cb16 (4 MB) + small buffers
    half8* cb16 = (half8*)d_ws;
    char* p = (char*)d_ws + (4 << 20);
    float* en = (float*)p;                  p += (size_t)K * 4;
    int* list = (int*)p;                    p += (size_t)N * 4;
    int* counter = (int*)p;                 p += 64;
    float* loss_accum = (float*)p;

    hipMemsetAsync(counter, 0, sizeof(int), stream);
    hipMemsetAsync(loss_accum, 0, sizeof(float), stream);
    cvt_hl_kernel<<<(N * 64) / 256, 256, 0, stream>>>(x, x16);
    cvt_hl_kernel<<<(K * 64) / 256, 256, 0, stream>>>(cb, cb16);
    enorm_kernel<<<(K * 64) / 256, 256, 0, stream>>>(cb, en, K);
    vq_mfma_kernel<<<N / BM, 512, 0, stream>>>(x16, cb16, en, x, cb, out,
                                               list, counter, loss_accum, N);
    rescan_kernel<<<512, 256, 0, stream>>>(x, cb, en, list, counter, out, loss_accum, N);
    loss_fin_kernel<<<1, 64, 0, stream>>>(loss_accum, out, (size_t)N * DDIM);
}

// Round 7
// 731.973 us; speedup vs baseline: 1.3067x; 1.2340x over previous
//
#include <hip/hip_runtime.h>
#include <stdint.h>

typedef _Float16 half8 __attribute__((ext_vector_type(8)));
typedef float f32x4 __attribute__((ext_vector_type(4)));

#define DDIM 256
#define KCODES 4096
#define BM 128
#define BN 256
#define NCH 8                  // 32-dim chunks per row
#define STEPS 128              // 16 tiles x 8 chunks
#define DELTA 0.02f
#define FLT_BIG 3.4e38f

#define GLOAD_LDS(gsrc, ldst)                                                        \
    __builtin_amdgcn_global_load_lds(                                                \
        (const __attribute__((address_space(1))) void*)(const void*)(gsrc),          \
        (__attribute__((address_space(3))) void*)(void*)(ldst), 16, 0, 0)

// ---------- fp32 -> hi/lo fp16, layout [row][ch(8)][slot(8)] half8 ----------
__global__ void cvt_hl_kernel(const float* __restrict__ src, half8* __restrict__ dst) {
    int gid = blockIdx.x * 256 + threadIdx.x;
    int p = gid & 7;
    int ch = (gid >> 3) & 7;
    long row = gid >> 6;
    int part = p >> 2, quad = p & 3;
    const float* s = src + row * DDIM + ch * 32 + quad * 8;
    half8 h;
    #pragma unroll
    for (int j = 0; j < 8; ++j) {
        float v = s[j];
        _Float16 hi = (_Float16)v;
        h[j] = part ? (_Float16)(v - (float)hi) : hi;
    }
    dst[gid] = h;
}

__global__ void enorm_kernel(const float* __restrict__ cb, float* __restrict__ en, int K) {
    int gid = blockIdx.x * blockDim.x + threadIdx.x;
    int code = gid >> 6;
    int lane = threadIdx.x & 63;
    if (code >= K) return;
    const float4 v = *reinterpret_cast<const float4*>(&cb[(size_t)code * DDIM + lane * 4]);
    float s = v.x * v.x + v.y * v.y + v.z * v.z + v.w * v.w;
    #pragma unroll
    for (int off = 32; off > 0; off >>= 1) s += __shfl_xor(s, off, 64);
    if (lane == 0) en[code] = s;
}

// ---------------- main: single-barrier pipelined MFMA GEMM + argmin + gather ----------------
__global__ __launch_bounds__(512, 2)
void vq_mfma_kernel(const half8* x16, const half8* __restrict__ cb16,
                    const float* __restrict__ en, const float* __restrict__ x,
                    const float* __restrict__ cb, float* out,
                    int* __restrict__ list, int* __restrict__ counter,
                    float* __restrict__ loss_accum, int N) {
    __shared__ __align__(16) half8 Abuf[2][BM * 8];   // 2 x 16 KB
    __shared__ __align__(16) half8 Bbuf[2][BN * 8];   // 2 x 32 KB
    __shared__ float en_lds[KCODES];                  // 16 KB
    __shared__ float red_d[4][BM];
    __shared__ float red_d2[4][BM];
    __shared__ int   red_i[4][BM];
    __shared__ int   binfo[BM];
    __shared__ float wsum[8];

    const int tid = threadIdx.x;
    const int lane = tid & 63;
    const int w = tid >> 6;
    const int wr = w >> 2, wc = w & 3;       // 2 x 4 waves, wave-tile 64 rows x 64 codes
    const int l15 = lane & 15, l4 = lane >> 4;
    const int brow = blockIdx.x * BM;
    const size_t ND = (size_t)N * DDIM;

    ((float4*)en_lds)[tid] = ((const float4*)en)[tid];
    ((float4*)en_lds)[tid + 512] = ((const float4*)en)[tid + 512];

    // ---- persistent stage pointers (strength-reduced) ----
    const int lrow = lane >> 3;          // row within 8-row region
    const int swz = (lane & 7) ^ lrow;   // pre-swizzled source slot
    const half8* pA0 = x16 + ((size_t)(brow + w * 8       + lrow) * NCH) * 8 + swz;
    const half8* pA1 = x16 + ((size_t)(brow + (w + 8) * 8 + lrow) * NCH) * 8 + swz;
    const half8* pB0 = cb16 + ((size_t)((w     ) * 8 + lrow) * NCH) * 8 + swz;
    const half8* pB1 = cb16 + ((size_t)((w +  8) * 8 + lrow) * NCH) * 8 + swz;
    const half8* pB2 = cb16 + ((size_t)((w + 16) * 8 + lrow) * NCH) * 8 + swz;
    const half8* pB3 = cb16 + ((size_t)((w + 24) * 8 + lrow) * NCH) * 8 + swz;

#define STAGE(b_) do {                                      \
        GLOAD_LDS(pA0, &Abuf[b_][(w     ) * 64]);           \
        GLOAD_LDS(pA1, &Abuf[b_][(w +  8) * 64]);           \
        GLOAD_LDS(pB0, &Bbuf[b_][(w     ) * 64]);           \
        GLOAD_LDS(pB1, &Bbuf[b_][(w +  8) * 64]);           \
        GLOAD_LDS(pB2, &Bbuf[b_][(w + 16) * 64]);           \
        GLOAD_LDS(pB3, &Bbuf[b_][(w + 24) * 64]);           \
    } while (0)

#define ADVANCE(t_) do {                                    \
        int dA = (((t_) & 7) == 7) ? -56 : 8;               \
        int dB = (((t_) & 7) == 7) ? 16328 : 8;             \
        pA0 += dA; pA1 += dA;                               \
        pB0 += dB; pB1 += dB; pB2 += dB; pB3 += dB;         \
    } while (0)

    // ---- LDS frag read bases (halfword units) ----
    const int sw7 = l15 & 7;
    const _Float16* A0 = (const _Float16*)Abuf;
    const _Float16* B0 = (const _Float16*)Bbuf;
    const _Float16* aH = A0 + wr * 4096 + l15 * 64 + ((l4    ) ^ sw7) * 8;
    const _Float16* aL = A0 + wr * 4096 + l15 * 64 + ((l4 + 4) ^ sw7) * 8;
    const _Float16* bH = B0 + wc * 4096 + l15 * 64 + ((l4    ) ^ sw7) * 8;
    const _Float16* bL = B0 + wc * 4096 + l15 * 64 + ((l4 + 4) ^ sw7) * 8;

    // prologue: stage steps 0 (buf0) and 1 (buf1)
    STAGE(0); ADVANCE(0);
    STAGE(1); ADVANCE(1);
    __syncthreads();           // drains vmcnt(0): both buffers + en_lds valid

    half8 Pah[4], Pal[4], Pbh[4], Pbl[4];   // even-step fragments
    half8 Qah[4], Qal[4], Qbh[4], Qbl[4];   // odd-step fragments

#define LOADF(T, AO, BO) do {                                         \
        _Pragma("unroll") for (int i_ = 0; i_ < 4; ++i_) {            \
            T##ah[i_] = *(const half8*)(aH + (AO) + i_ * 1024);       \
            T##al[i_] = *(const half8*)(aL + (AO) + i_ * 1024);       \
            T##bh[i_] = *(const half8*)(bH + (BO) + i_ * 1024);       \
            T##bl[i_] = *(const half8*)(bL + (BO) + i_ * 1024);       \
        }                                                             \
    } while (0)

    // operand-swapped: lane = x-row (col), regs = codes (row)
#define MFMA48(T) do {                                                \
        _Pragma("unroll") for (int m_ = 0; m_ < 4; ++m_)              \
        _Pragma("unroll") for (int n_ = 0; n_ < 4; ++n_) {            \
            acc[m_][n_] = __builtin_amdgcn_mfma_f32_16x16x32_f16(T##bh[m_], T##ah[n_], acc[m_][n_], 0, 0, 0); \
            acc[m_][n_] = __builtin_amdgcn_mfma_f32_16x16x32_f16(T##bl[m_], T##ah[n_], acc[m_][n_], 0, 0, 0); \
            acc[m_][n_] = __builtin_amdgcn_mfma_f32_16x16x32_f16(T##bh[m_], T##al[n_], acc[m_][n_], 0, 0, 0); \
        }                                                             \
    } while (0)

    f32x4 acc[4][4];
    float bestv[4], best2v[4];
    int bidv[4];
    #pragma unroll
    for (int i = 0; i < 4; ++i) { bestv[i] = FLT_BIG; best2v[i] = FLT_BIG; bidv[i] = 0; }

    LOADF(P, 0, 0);                                     // frags for step 0 (buf0)
    asm volatile("s_waitcnt lgkmcnt(0)" ::: "memory");  // regs valid before buf0 overwritten
    __builtin_amdgcn_sched_barrier(0);

    const int code_sub = wc * 64 + l4 * 4;

    for (int s = 0; s < STEPS; s += 2) {
        if ((s & 7) == 0) {
            #pragma unroll
            for (int m = 0; m < 4; ++m)
                #pragma unroll
                for (int n = 0; n < 4; ++n) acc[m][n] = (f32x4){0.f, 0.f, 0.f, 0.f};
        }
        // ---- even step s: compute P, prefetch Q (step s+1, buf1), stage s+2 (buf0) ----
        if (s + 2 < STEPS) { STAGE(0); ADVANCE(s + 2); }
        LOADF(Q, 8192, 16384);
        __builtin_amdgcn_s_setprio(1);
        MFMA48(P);
        __builtin_amdgcn_s_setprio(0);
        __syncthreads();

        // ---- odd step s+1: compute Q, prefetch P (step s+2, buf0), stage s+3 (buf1) ----
        if (s + 3 < STEPS) { STAGE(1); ADVANCE(s + 3); }
        if (s + 2 < STEPS) LOADF(P, 0, 0);
        __builtin_amdgcn_s_setprio(1);
        MFMA48(Q);
        __builtin_amdgcn_s_setprio(0);
        if ((s & 7) == 6) {   // step s+1 ends a 256-code tile
            const int c0 = ((s + 1) >> 3) * BN;
            #pragma unroll
            for (int m = 0; m < 4; ++m) {
                #pragma unroll
                for (int r = 0; r < 4; ++r) {
                    int code = c0 + code_sub + m * 16 + r;
                    float e = en_lds[code];
                    #pragma unroll
                    for (int n = 0; n < 4; ++n) {
                        float dist = fmaf(-2.f, acc[m][n][r], e);
                        if (dist < bestv[n]) { best2v[n] = bestv[n]; bestv[n] = dist; bidv[n] = code; }
                        else if (dist < best2v[n]) best2v[n] = dist;
                    }
                }
            }
        }
        __syncthreads();
    }
#undef STAGE
#undef ADVANCE
#undef LOADF
#undef MFMA48

    // ---- cross-lane merge: candidates for row (wr*64+n*16+l15) spread over l4 ----
    #pragma unroll
    for (int n = 0; n < 4; ++n) {
        float d = bestv[n], d2 = best2v[n];
        int ix = bidv[n];
        #pragma unroll
        for (int off = 16; off < 64; off <<= 1) {
            float od = __shfl_xor(d, off, 64);
            float od2 = __shfl_xor(d2, off, 64);
            int oi = __shfl_xor(ix, off, 64);
            if (od < d || (od == d && oi < ix)) { d2 = fminf(d, od2); d = od; ix = oi; }
            else d2 = fminf(d2, od);
        }
        if (l4 == 0) {
            int row = wr * 64 + n * 16 + l15;
            red_d[wc][row] = d;
            red_d2[wc][row] = d2;
            red_i[wc][row] = ix;
        }
    }
    __syncthreads();

    // ---- cross-wave merge + index write + flag append ----
    if (tid < BM) {
        float d = red_d[0][tid], d2 = red_d2[0][tid];
        int ix = red_i[0][tid];
        #pragma unroll
        for (int q = 1; q < 4; ++q) {
            float od = red_d[q][tid], od2 = red_d2[q][tid];
            int oi = red_i[q][tid];
            if (od < d || (od == d && oi < ix)) { d2 = fminf(d, od2); d = od; ix = oi; }
            else d2 = fminf(d2, od);
        }
        int fl = (d2 - d < DELTA) ? 1 : 0;
        out[ND + 1 + brow + tid] = (float)ix;
        binfo[tid] = ix | (fl << 16);
        if (fl) {
            int pos = atomicAdd(counter, 1);
            list[pos] = brow + tid;
        }
    }
    __syncthreads();

    // ---- fused gather + loss (flagged rows: provisional write, no loss) ----
    float lsum = 0.f;
    #pragma unroll 4
    for (int pp = 0; pp < 16; ++pp) {
        int i = tid + pp * 512;       // 0..8191 float4-units
        int row = i >> 6;
        int c4 = (i & 63) << 2;
        int info = binfo[row];
        int code = info & 0xffff;
        const float4 q = *reinterpret_cast<const float4*>(&cb[(size_t)code * DDIM + c4]);
        const float4 xv = *reinterpret_cast<const float4*>(&x[(size_t)(brow + row) * DDIM + c4]);
        float d0 = xv.x - q.x, d1 = xv.y - q.y, d2 = xv.z - q.z, d3 = xv.w - q.w;
        if (!(info >> 16)) lsum += d0 * d0 + d1 * d1 + d2 * d2 + d3 * d3;
        *reinterpret_cast<float4*>(&out[(size_t)(brow + row) * DDIM + c4]) = q;
    }
    #pragma unroll
    for (int off = 32; off > 0; off >>= 1) lsum += __shfl_xor(lsum, off, 64);
    if (lane == 0) wsum[w] = lsum;
    __syncthreads();
    if (tid == 0) {
        float tot = 0.f;
        #pragma unroll
        for (int q = 0; q < 8; ++q) tot += wsum[q];
        atomicAdd(loss_accum, tot * (0.25f / (float)ND));
    }
}

// ---------------- exact fp32 rescan: repairs flagged rows completely ----------------
__global__ __launch_bounds__(256)
void rescan_kernel(const float* __restrict__ x, const float* __restrict__ cb,
                   const float* __restrict__ en, const int* __restrict__ list,
                   const int* __restrict__ counter, float* out,
                   float* __restrict__ loss_accum, int N) {
    __shared__ __align__(16) float4 xrow4[64];
    __shared__ float wd[4];
    __shared__ int wi[4];
    __shared__ float wls[4];
    __shared__ int six;
    const int tid = threadIdx.x;
    const int w = tid >> 6;
    const int lane = tid & 63;
    const int cnt = *counter;
    const size_t ND = (size_t)N * DDIM;

    for (int it = blockIdx.x; it < cnt; it += gridDim.x) {
        const int row = list[it];
        __syncthreads();
        if (tid < 64) xrow4[tid] = ((const float4*)&x[(size_t)row * DDIM])[tid];
        __syncthreads();
        const float4 xv = xrow4[lane];
        float bd = FLT_BIG;
        int bi = 0;
        for (int i = 0; i < KCODES / 4; ++i) {
            int code = i * 4 + w;
            const float4 c4 = ((const float4*)&cb[(size_t)code * DDIM])[lane];
            float s = xv.x * c4.x + xv.y * c4.y + xv.z * c4.z + xv.w * c4.w;
            #pragma unroll
            for (int off = 1; off < 64; off <<= 1) s += __shfl_xor(s, off, 64);
            float dist = fmaf(-2.f, s, en[code]);
            if (dist < bd) { bd = dist; bi = code; }
        }
        if (lane == 0) { wd[w] = bd; wi[w] = bi; }
        __syncthreads();
        if (tid == 0) {
            float d = wd[0]; int ix = wi[0];
            #pragma unroll
            for (int q = 1; q < 4; ++q) {
                if (wd[q] < d || (wd[q] == d && wi[q] < ix)) { d = wd[q]; ix = wi[q]; }
            }
            six = ix;
            out[ND + 1 + row] = (float)ix;
        }
        __syncthreads();
        const int ix = six;
        float c = cb[(size_t)ix * DDIM + tid];
        float xs = ((const float*)xrow4)[tid];
        out[(size_t)row * DDIM + tid] = c;
        float dd = xs - c;
        float ss = dd * dd;
        #pragma unroll
        for (int off = 32; off > 0; off >>= 1) ss += __shfl_xor(ss, off, 64);
        if (lane == 0) wls[w] = ss;
        __syncthreads();
        if (tid == 0) {
            float tot = wls[0] + wls[1] + wls[2] + wls[3];
            atomicAdd(loss_accum, tot * (0.25f / (float)ND));
        }
    }
}

__global__ void loss_fin_kernel(const float* __restrict__ loss_accum,
                                float* __restrict__ out, size_t off) {
    if (blockIdx.x == 0 && threadIdx.x == 0) out[off] = *loss_accum;
}

extern "C" void kernel_launch(void* const* d_in, const int* in_sizes, int n_in,
                              void* d_out, int out_size, void* d_ws, size_t ws_size,
                              hipStream_t stream) {
    const float* x = (const float*)d_in[0];
    const float* cb = (const float*)d_in[1];
    const int N = in_sizes[0] / DDIM;    // 65536
    const int K = in_sizes[1] / DDIM;    // 4096
    float* out = (float*)d_out;

    // x16 (64 MB) lives in out[0 .. N*D) — each block reads only its own rows,
    // then overwrites them in its fused gather epilogue
    half8* x16 = (half8*)d_out;

    half8* cb16 = (half8*)d_ws;          // 4 MB
    char* p = (char*)d_ws + (4 << 20);
    float* en = (float*)p;                  p += (size_t)K * 4;
    int* list = (int*)p;                    p += (size_t)N * 4;
    int* counter = (int*)p;                 p += 64;
    float* loss_accum = (float*)p;

    hipMemsetAsync(counter, 0, sizeof(int), stream);
    hipMemsetAsync(loss_accum, 0, sizeof(float), stream);
    cvt_hl_kernel<<<(N * 64) / 256, 256, 0, stream>>>(x, x16);
    cvt_hl_kernel<<<(K * 64) / 256, 256, 0, stream>>>(cb, cb16);
    enorm_kernel<<<(K * 64) / 256, 256, 0, stream>>>(cb, en, K);
    vq_mfma_kernel<<<N / BM, 512, 0, stream>>>(x16, cb16, en, x, cb, out,
                                               list, counter, loss_accum, N);
    rescan_kernel<<<512, 256, 0, stream>>>(x, cb, en, list, counter, out, loss_accum, N);
    loss_fin_kernel<<<1, 64, 0, stream>>>(loss_accum, out, (size_t)N * DDIM);
}

// Round 8
// 710.618 us; speedup vs baseline: 1.3459x; 1.0301x over previous
//
#include <hip/hip_runtime.h>
#include <stdint.h>

typedef _Float16 half8 __attribute__((ext_vector_type(8)));
typedef float f32x4 __attribute__((ext_vector_type(4)));

#define DDIM 256
#define KCODES 4096
#define BM 128
#define BN 256
#define NCH 8                  // 32-dim chunks per row
#define STEPS 128              // 16 tiles x 8 chunks
#define DELTA 0.02f
#define FLT_BIG 3.4e38f

#define GLOAD_LDS(gsrc, ldst)                                                        \
    __builtin_amdgcn_global_load_lds(                                                \
        (const __attribute__((address_space(1))) void*)(const void*)(gsrc),          \
        (__attribute__((address_space(3))) void*)(void*)(ldst), 16, 0, 0)

// ---------- fp32 -> hi/lo fp16, layout [row][ch(8)][slot(8)] half8 ----------
__global__ void cvt_hl_kernel(const float* __restrict__ src, half8* __restrict__ dst) {
    int gid = blockIdx.x * 256 + threadIdx.x;
    int p = gid & 7;
    int ch = (gid >> 3) & 7;
    long row = gid >> 6;
    int part = p >> 2, quad = p & 3;
    const float* s = src + row * DDIM + ch * 32 + quad * 8;
    half8 h;
    #pragma unroll
    for (int j = 0; j < 8; ++j) {
        float v = s[j];
        _Float16 hi = (_Float16)v;
        h[j] = part ? (_Float16)(v - (float)hi) : hi;
    }
    dst[gid] = h;
}

__global__ void enorm_kernel(const float* __restrict__ cb, float* __restrict__ en, int K) {
    int gid = blockIdx.x * blockDim.x + threadIdx.x;
    int code = gid >> 6;
    int lane = threadIdx.x & 63;
    if (code >= K) return;
    const float4 v = *reinterpret_cast<const float4*>(&cb[(size_t)code * DDIM + lane * 4]);
    float s = v.x * v.x + v.y * v.y + v.z * v.z + v.w * v.w;
    #pragma unroll
    for (int off = 32; off > 0; off >>= 1) s += __shfl_xor(s, off, 64);
    if (lane == 0) en[code] = s;
}

// ---------------- main: stage-after-barrier pipelined MFMA GEMM + argmin + gather ----------------
__global__ __launch_bounds__(512, 2)
void vq_mfma_kernel(const half8* x16, const half8* __restrict__ cb16,
                    const float* __restrict__ en, const float* __restrict__ x,
                    const float* __restrict__ cb, float* out,
                    int* __restrict__ list, int* __restrict__ counter,
                    float* __restrict__ loss_accum, int N) {
    __shared__ __align__(16) half8 Abuf[2][BM * 8];   // 2 x 16 KB
    __shared__ __align__(16) half8 Bbuf[2][BN * 8];   // 2 x 32 KB
    __shared__ float en_lds[KCODES];                  // 16 KB
    __shared__ float red_d[4][BM];
    __shared__ float red_d2[4][BM];
    __shared__ int   red_i[4][BM];
    __shared__ int   binfo[BM];
    __shared__ float wsum[8];

    const int tid = threadIdx.x;
    const int lane = tid & 63;
    const int w = tid >> 6;
    const int wr = w >> 2, wc = w & 3;       // 2 x 4 waves, wave-tile 64 rows x 64 codes
    const int l15 = lane & 15, l4 = lane >> 4;
    const int brow = blockIdx.x * BM;
    const size_t ND = (size_t)N * DDIM;

    ((float4*)en_lds)[tid] = ((const float4*)en)[tid];
    ((float4*)en_lds)[tid + 512] = ((const float4*)en)[tid + 512];

    // ---- persistent stage pointers (strength-reduced) ----
    const int lrow = lane >> 3;          // row within 8-row region
    const int swz = (lane & 7) ^ lrow;   // pre-swizzled source slot
    const half8* pA0 = x16 + ((size_t)(brow + w * 8       + lrow) * NCH) * 8 + swz;
    const half8* pA1 = x16 + ((size_t)(brow + (w + 8) * 8 + lrow) * NCH) * 8 + swz;
    const half8* pB0 = cb16 + ((size_t)((w     ) * 8 + lrow) * NCH) * 8 + swz;
    const half8* pB1 = cb16 + ((size_t)((w +  8) * 8 + lrow) * NCH) * 8 + swz;
    const half8* pB2 = cb16 + ((size_t)((w + 16) * 8 + lrow) * NCH) * 8 + swz;
    const half8* pB3 = cb16 + ((size_t)((w + 24) * 8 + lrow) * NCH) * 8 + swz;

#define STAGE(b_) do {                                      \
        GLOAD_LDS(pA0, &Abuf[b_][(w     ) * 64]);           \
        GLOAD_LDS(pA1, &Abuf[b_][(w +  8) * 64]);           \
        GLOAD_LDS(pB0, &Bbuf[b_][(w     ) * 64]);           \
        GLOAD_LDS(pB1, &Bbuf[b_][(w +  8) * 64]);           \
        GLOAD_LDS(pB2, &Bbuf[b_][(w + 16) * 64]);           \
        GLOAD_LDS(pB3, &Bbuf[b_][(w + 24) * 64]);           \
    } while (0)

    // advance pointers past step t (rollover when t is last chunk of a tile)
#define ADVANCE(roll_) do {                                 \
        const int dA = (roll_) ? -56 : 8;                   \
        const int dB = (roll_) ? 16328 : 8;                 \
        pA0 += dA; pA1 += dA;                               \
        pB0 += dB; pB1 += dB; pB2 += dB; pB3 += dB;         \
    } while (0)

    // ---- LDS frag read bases (halfword units) ----
    const int sw7 = l15 & 7;
    const _Float16* A0 = (const _Float16*)Abuf;
    const _Float16* B0 = (const _Float16*)Bbuf;
    const _Float16* aH = A0 + wr * 4096 + l15 * 64 + ((l4    ) ^ sw7) * 8;
    const _Float16* aL = A0 + wr * 4096 + l15 * 64 + ((l4 + 4) ^ sw7) * 8;
    const _Float16* bH = B0 + wc * 4096 + l15 * 64 + ((l4    ) ^ sw7) * 8;
    const _Float16* bL = B0 + wc * 4096 + l15 * 64 + ((l4 + 4) ^ sw7) * 8;

    // prologue: stage step 0 into buf0 (drained by the first __syncthreads)
    STAGE(0); ADVANCE(0 /*step0, no rollover*/);

    float bestv[4], best2v[4];
    int bidv[4];
    #pragma unroll
    for (int i = 0; i < 4; ++i) { bestv[i] = FLT_BIG; best2v[i] = FLT_BIG; bidv[i] = 0; }

    const int code_sub = wc * 64 + l4 * 4;
    f32x4 acc[4][4];

    for (int it = 0; it < 16; ++it) {
        #pragma unroll
        for (int m = 0; m < 4; ++m)
            #pragma unroll
            for (int n = 0; n < 4; ++n) acc[m][n] = (f32x4){0.f, 0.f, 0.f, 0.f};

        #pragma unroll
        for (int k = 0; k < 8; ++k) {
            // drains vmcnt of the stage issued one full step earlier, then publishes
            __syncthreads();
            // stage step s+1 into the other buffer (issued EARLY in the step)
            if (k != 7) {
                STAGE((k + 1) & 1);
                ADVANCE(k == 6);
            } else if (it != 15) {
                STAGE(0);          // step (it+1)*8, parity 0
                ADVANCE(0);
            }
            __builtin_amdgcn_sched_barrier(0);   // pin stage issue before reads/MFMA

            const int ao = (k & 1) ? 8192 : 0;
            const int bo = (k & 1) ? 16384 : 0;
            half8 ah[4], al[4], bh[4], bl[4];
            #pragma unroll
            for (int i = 0; i < 4; ++i) {
                ah[i] = *(const half8*)(aH + ao + i * 1024);
                al[i] = *(const half8*)(aL + ao + i * 1024);
                bh[i] = *(const half8*)(bH + bo + i * 1024);
                bl[i] = *(const half8*)(bL + bo + i * 1024);
            }
            __builtin_amdgcn_s_setprio(1);
            #pragma unroll
            for (int m = 0; m < 4; ++m)
                #pragma unroll
                for (int n = 0; n < 4; ++n) {
                    acc[m][n] = __builtin_amdgcn_mfma_f32_16x16x32_f16(bh[m], ah[n], acc[m][n], 0, 0, 0);
                    acc[m][n] = __builtin_amdgcn_mfma_f32_16x16x32_f16(bl[m], ah[n], acc[m][n], 0, 0, 0);
                    acc[m][n] = __builtin_amdgcn_mfma_f32_16x16x32_f16(bh[m], al[n], acc[m][n], 0, 0, 0);
                }
            __builtin_amdgcn_s_setprio(0);
        }

        // ---- tile epilogue: dist = ||e||^2 - 2*dot ----
        const int c0 = it * BN;
        #pragma unroll
        for (int m = 0; m < 4; ++m) {
            #pragma unroll
            for (int r = 0; r < 4; ++r) {
                int code = c0 + code_sub + m * 16 + r;
                float e = en_lds[code];
                #pragma unroll
                for (int n = 0; n < 4; ++n) {
                    float dist = fmaf(-2.f, acc[m][n][r], e);
                    if (dist < bestv[n]) { best2v[n] = bestv[n]; bestv[n] = dist; bidv[n] = code; }
                    else if (dist < best2v[n]) best2v[n] = dist;
                }
            }
        }
    }
#undef STAGE
#undef ADVANCE

    // ---- cross-lane merge: candidates for row (wr*64+n*16+l15) spread over l4 ----
    #pragma unroll
    for (int n = 0; n < 4; ++n) {
        float d = bestv[n], d2 = best2v[n];
        int ix = bidv[n];
        #pragma unroll
        for (int off = 16; off < 64; off <<= 1) {
            float od = __shfl_xor(d, off, 64);
            float od2 = __shfl_xor(d2, off, 64);
            int oi = __shfl_xor(ix, off, 64);
            if (od < d || (od == d && oi < ix)) { d2 = fminf(d, od2); d = od; ix = oi; }
            else d2 = fminf(d2, od);
        }
        if (l4 == 0) {
            int row = wr * 64 + n * 16 + l15;
            red_d[wc][row] = d;
            red_d2[wc][row] = d2;
            red_i[wc][row] = ix;
        }
    }
    __syncthreads();

    // ---- cross-wave merge + index write + flag append ----
    if (tid < BM) {
        float d = red_d[0][tid], d2 = red_d2[0][tid];
        int ix = red_i[0][tid];
        #pragma unroll
        for (int q = 1; q < 4; ++q) {
            float od = red_d[q][tid], od2 = red_d2[q][tid];
            int oi = red_i[q][tid];
            if (od < d || (od == d && oi < ix)) { d2 = fminf(d, od2); d = od; ix = oi; }
            else d2 = fminf(d2, od);
        }
        int fl = (d2 - d < DELTA) ? 1 : 0;
        out[ND + 1 + brow + tid] = (float)ix;
        binfo[tid] = ix | (fl << 16);
        if (fl) {
            int pos = atomicAdd(counter, 1);
            list[pos] = brow + tid;
        }
    }
    __syncthreads();

    // ---- fused gather + loss (flagged rows: provisional write, no loss) ----
    float lsum = 0.f;
    #pragma unroll 4
    for (int pp = 0; pp < 16; ++pp) {
        int i = tid + pp * 512;       // 0..8191 float4-units
        int row = i >> 6;
        int c4 = (i & 63) << 2;
        int info = binfo[row];
        int code = info & 0xffff;
        const float4 q = *reinterpret_cast<const float4*>(&cb[(size_t)code * DDIM + c4]);
        const float4 xv = *reinterpret_cast<const float4*>(&x[(size_t)(brow + row) * DDIM + c4]);
        float d0 = xv.x - q.x, d1 = xv.y - q.y, d2 = xv.z - q.z, d3 = xv.w - q.w;
        if (!(info >> 16)) lsum += d0 * d0 + d1 * d1 + d2 * d2 + d3 * d3;
        *reinterpret_cast<float4*>(&out[(size_t)(brow + row) * DDIM + c4]) = q;
    }
    #pragma unroll
    for (int off = 32; off > 0; off >>= 1) lsum += __shfl_xor(lsum, off, 64);
    if (lane == 0) wsum[w] = lsum;
    __syncthreads();
    if (tid == 0) {
        float tot = 0.f;
        #pragma unroll
        for (int q = 0; q < 8; ++q) tot += wsum[q];
        atomicAdd(loss_accum, tot * (0.25f / (float)ND));
    }
}

// ---------------- exact fp32 rescan: repairs flagged rows completely ----------------
__global__ __launch_bounds__(256)
void rescan_kernel(const float* __restrict__ x, const float* __restrict__ cb,
                   const float* __restrict__ en, const int* __restrict__ list,
                   const int* __restrict__ counter, float* out,
                   float* __restrict__ loss_accum, int N) {
    __shared__ __align__(16) float4 xrow4[64];
    __shared__ float wd[4];
    __shared__ int wi[4];
    __shared__ float wls[4];
    __shared__ int six;
    const int tid = threadIdx.x;
    const int w = tid >> 6;
    const int lane = tid & 63;
    const int cnt = *counter;
    const size_t ND = (size_t)N * DDIM;

    for (int it = blockIdx.x; it < cnt; it += gridDim.x) {
        const int row = list[it];
        __syncthreads();
        if (tid < 64) xrow4[tid] = ((const float4*)&x[(size_t)row * DDIM])[tid];
        __syncthreads();
        const float4 xv = xrow4[lane];
        float bd = FLT_BIG;
        int bi = 0;
        for (int i = 0; i < KCODES / 4; ++i) {
            int code = i * 4 + w;
            const float4 c4 = ((const float4*)&cb[(size_t)code * DDIM])[lane];
            float s = xv.x * c4.x + xv.y * c4.y + xv.z * c4.z + xv.w * c4.w;
            #pragma unroll
            for (int off = 1; off < 64; off <<= 1) s += __shfl_xor(s, off, 64);
            float dist = fmaf(-2.f, s, en[code]);
            if (dist < bd) { bd = dist; bi = code; }
        }
        if (lane == 0) { wd[w] = bd; wi[w] = bi; }
        __syncthreads();
        if (tid == 0) {
            float d = wd[0]; int ix = wi[0];
            #pragma unroll
            for (int q = 1; q < 4; ++q) {
                if (wd[q] < d || (wd[q] == d && wi[q] < ix)) { d = wd[q]; ix = wi[q]; }
            }
            six = ix;
            out[ND + 1 + row] = (float)ix;
        }
        __syncthreads();
        const int ix = six;
        float c = cb[(size_t)ix * DDIM + tid];
        float xs = ((const float*)xrow4)[tid];
        out[(size_t)row * DDIM + tid] = c;
        float dd = xs - c;
        float ss = dd * dd;
        #pragma unroll
        for (int off = 32; off > 0; off >>= 1) ss += __shfl_xor(ss, off, 64);
        if (lane == 0) wls[w] = ss;
        __syncthreads();
        if (tid == 0) {
            float tot = wls[0] + wls[1] + wls[2] + wls[3];
            atomicAdd(loss_accum, tot * (0.25f / (float)ND));
        }
    }
}

__global__ void loss_fin_kernel(const float* __restrict__ loss_accum,
                                float* __restrict__ out, size_t off) {
    if (blockIdx.x == 0 && threadIdx.x == 0) out[off] = *loss_accum;
}

extern "C" void kernel_launch(void* const* d_in, const int* in_sizes, int n_in,
                              void* d_out, int out_size, void* d_ws, size_t ws_size,
                              hipStream_t stream) {
    const float* x = (const float*)d_in[0];
    const float* cb = (const float*)d_in[1];
    const int N = in_sizes[0] / DDIM;    // 65536
    const int K = in_sizes[1] / DDIM;    // 4096
    float* out = (float*)d_out;

    // x16 (64 MB) lives in out[0 .. N*D) — each block reads only its own rows,
    // then overwrites them in its fused gather epilogue
    half8* x16 = (half8*)d_out;

    half8* cb16 = (half8*)d_ws;          // 4 MB
    char* p = (char*)d_ws + (4 << 20);
    float* en = (float*)p;                  p += (size_t)K * 4;
    int* list = (int*)p;                    p += (size_t)N * 4;
    int* counter = (int*)p;                 p += 64;
    float* loss_accum = (float*)p;

    hipMemsetAsync(counter, 0, sizeof(int), stream);
    hipMemsetAsync(loss_accum, 0, sizeof(float), stream);
    cvt_hl_kernel<<<(N * 64) / 256, 256, 0, stream>>>(x, x16);
    cvt_hl_kernel<<<(K * 64) / 256, 256, 0, stream>>>(cb, cb16);
    enorm_kernel<<<(K * 64) / 256, 256, 0, stream>>>(cb, en, K);
    vq_mfma_kernel<<<N / BM, 512, 0, stream>>>(x16, cb16, en, x, cb, out,
                                               list, counter, loss_accum, N);
    rescan_kernel<<<512, 256, 0, stream>>>(x, cb, en, list, counter, out, loss_accum, N);
    loss_fin_kernel<<<1, 64, 0, stream>>>(loss_accum, out, (size_t)N * DDIM);
}